// Round 5
// baseline (259.865 us; speedup 1.0000x reference)
//
#include <hip/hip_runtime.h>

// Problem constants (B=4, S=4096, D=2048, E=8, K=2, cap_factor=1.25)
#define TOKENS      16384
#define DIM         2048
#define D4          512          // DIM / 4 (float4 units)
#define NE          8            // experts
#define CAPACITY    5120         // int(16384*2/8*1.25)
#define NASSIGN     (TOKENS * 2) // 32768 top-k assignments

#define NTHREADS    512          // 8 waves/block
#define NBLOCKS     512          // 4096 waves; 4 tokens (2 pairs) per wave

// d_out layout (all float32, tuple order):
//   [0, 32768)        expert_indices as float  [B,S,K]
//   [32768, 65536)    expert_weights           [B,S,K]
//   [65536]           load_balance_loss
//   [65537, 98305)    expert_mask              [B,S,K]

__device__ __forceinline__ float dot4(const float4 a, const float4 b) {
    return a.x * b.x + a.y * b.y + a.z * b.z + a.w * b.w;
}

// Compute logits for a token PAIR from pre-landed x registers + LDS-resident w.
// Each w ds_read feeds both tokens (halves the LDS-pipe cost per token — the
// w re-read, 64KB/token, is the non-HBM bottleneck of this kernel).
__device__ __forceinline__ void process_pair(
    const float4 (&xr)[2][8], int t0, const float4* __restrict__ wlds, int lane,
    float* __restrict__ imp_lds, int* __restrict__ cnt_lds,
    float* __restrict__ out_idx, float* __restrict__ out_w)
{
    float acc0[NE], acc1[NE];
#pragma unroll
    for (int e = 0; e < NE; e++) { acc0[e] = 0.f; acc1[e] = 0.f; }

#pragma unroll
    for (int c = 0; c < 8; c++) {
#pragma unroll
        for (int e = 0; e < NE; e++) {
            const float4 w = wlds[e * D4 + c * 64 + lane];  // 1KB/instr, conflict-free
            acc0[e] += dot4(xr[0][c], w);
            acc1[e] += dot4(xr[1][c], w);
        }
    }

    // fold (xor 1): even lanes keep token0, odd lanes token1; then butterfly.
    const int p1 = lane & 1;
    float v[NE];
#pragma unroll
    for (int e = 0; e < NE; e++) {
        float snd = p1 ? acc0[e] : acc1[e];
        float kp  = p1 ? acc1[e] : acc0[e];
        v[e] = kp + __shfl_xor(snd, 1, 64);
    }
#pragma unroll
    for (int off = 2; off <= 32; off <<= 1) {
#pragma unroll
        for (int e = 0; e < NE; e++) v[e] += __shfl_xor(v[e], off, 64);
    }
    // lane 0 holds full logits of token t0, lane 1 of token t0+1

    if (lane < 2) {
        const int t = t0 + lane;

        // softmax over 8 (importance)
        float m = v[0];
#pragma unroll
        for (int e = 1; e < NE; e++) m = fmaxf(m, v[e]);
        float pe[NE], s = 0.f;
#pragma unroll
        for (int e = 0; e < NE; e++) { pe[e] = expf(v[e] - m); s += pe[e]; }
        const float inv = 1.f / s;
#pragma unroll
        for (int e = 0; e < NE; e++) atomicAdd(&imp_lds[e], pe[e] * inv);

        // top-2 (ties -> lowest index, jax top_k semantics)
        int i1 = 0; float v1 = v[0];
#pragma unroll
        for (int e = 1; e < NE; e++) { if (v[e] > v1) { v1 = v[e]; i1 = e; } }
        int i2 = -1; float v2 = -3.4e38f;
#pragma unroll
        for (int e = 0; e < NE; e++) { if (e != i1 && v[e] > v2) { v2 = v[e]; i2 = e; } }

        const float w1 = 1.f / (1.f + expf(v2 - v1));   // renormalized pair
        atomicAdd(&cnt_lds[i1], 1);
        atomicAdd(&cnt_lds[i2], 1);

        out_idx[2 * t]     = (float)i1;
        out_idx[2 * t + 1] = (float)i2;
        out_w[2 * t]       = w1;
        out_w[2 * t + 1]   = 1.f - w1;
    }
}

// Structure: stage w -> barrier -> issue ALL 32 x-loads (16 KB/wave in flight,
// two pairs deep) -> pure LDS+VALU compute. Exactly one latency exposure; no
// barriers or per-chunk global round-trips in the compute path.
__global__ __launch_bounds__(NTHREADS) void router_main(
    const float* __restrict__ x, const float* __restrict__ wg,
    float* __restrict__ out_idx, float* __restrict__ out_w,
    float* __restrict__ imp_g, int* __restrict__ cnt_g)
{
    __shared__ float4 wlds[NE * D4];     // 64 KiB
    __shared__ float  imp_lds[NE];
    __shared__ int    cnt_lds[NE];

    const int tid  = threadIdx.x;
    const int lane = tid & 63;
    const int wave = tid >> 6;
    const int q    = blockIdx.x * (NTHREADS / 64) + wave;  // 0..4095
    const int tok0 = q * 4;   // wave covers tokens tok0..tok0+3 (32 KB contig)

    if (tid < NE) { imp_lds[tid] = 0.f; cnt_lds[tid] = 0; }

    const float4* x4  = (const float4*)x;
    const float4* wg4 = (const float4*)wg;
    const float4* xb  = x4 + (size_t)tok0 * D4 + lane;

    // Issue pair-A x loads first: they stream from HBM while we stage w.
    float4 xA[2][8];
#pragma unroll
    for (int c = 0; c < 8; c++) { xA[0][c] = xb[c * 64]; }
#pragma unroll
    for (int c = 0; c < 8; c++) { xA[1][c] = xb[D4 + c * 64]; }

    // Stage w (64 KiB) into LDS: 8 float4 per thread, coalesced.
#pragma unroll
    for (int k = 0; k < (NE * D4) / NTHREADS; k++)
        wlds[tid + k * NTHREADS] = wg4[tid + k * NTHREADS];
    __syncthreads();

    // Issue pair-B loads now so they're in flight during pair-A compute.
    float4 xB[2][8];
#pragma unroll
    for (int c = 0; c < 8; c++) { xB[0][c] = xb[2 * D4 + c * 64]; }
#pragma unroll
    for (int c = 0; c < 8; c++) { xB[1][c] = xb[3 * D4 + c * 64]; }
    __builtin_amdgcn_sched_barrier(0);   // pin: loads issued before compute

    process_pair(xA, tok0,     wlds, lane, imp_lds, cnt_lds, out_idx, out_w);
    process_pair(xB, tok0 + 2, wlds, lane, imp_lds, cnt_lds, out_idx, out_w);

    __syncthreads();
    if (tid < NE)          atomicAdd(&imp_g[tid], imp_lds[tid]);
    else if (tid < 2 * NE) atomicAdd(&cnt_g[tid - NE], cnt_lds[tid - NE]);
}

// Capacity mask (exact rank rule, matches lexsort((-wf, idxf)) + rank<capacity)
// plus the load-balance loss scalar.
__global__ void mask_loss_kernel(
    const float* __restrict__ out_idx, const float* __restrict__ out_w,
    float* __restrict__ mask, float* __restrict__ loss_out,
    const float* __restrict__ imp_g, const int* __restrict__ cnt_g)
{
    const int i = blockIdx.x * blockDim.x + threadIdx.x;
    if (i < NASSIGN) {
        const int e = (int)out_idx[i];
        const int c = cnt_g[e];
        float mk = 1.f;
        if (c > CAPACITY) {   // statistically never taken; exact fallback
            const float wi = out_w[i];
            int rank = 0;
            for (int j = 0; j < NASSIGN; j++) {
                if ((int)out_idx[j] == e) {
                    const float wj = out_w[j];
                    if (wj > wi || (wj == wi && j < i)) rank++;
                }
            }
            mk = (rank < CAPACITY) ? 1.f : 0.f;
        }
        mask[i] = mk;
    }
    if (blockIdx.x == 0 && threadIdx.x == 0) {
        float si = 0.f, sc = 0.f, dot = 0.f;
#pragma unroll
        for (int e = 0; e < NE; e++) {
            const float im = imp_g[e];
            const float ct = (float)cnt_g[e];
            si += im; sc += ct; dot += im * ct;
        }
        loss_out[0] = (float)NE * dot / (si * sc);
    }
}

extern "C" void kernel_launch(void* const* d_in, const int* in_sizes, int n_in,
                              void* d_out, int out_size, void* d_ws, size_t ws_size,
                              hipStream_t stream)
{
    const float* x  = (const float*)d_in[0];   // [4,4096,2048] f32
    const float* wg = (const float*)d_in[1];   // [8,2048] f32

    float* out      = (float*)d_out;
    float* out_idx  = out;            // 32768
    float* out_w    = out + 32768;    // 32768
    float* loss     = out + 65536;    // 1
    float* mask     = out + 65537;    // 32768

    float* imp_g = (float*)d_ws;                     // 8 f32
    int*   cnt_g = (int*)((char*)d_ws + 64);         // 8 i32

    hipMemsetAsync(d_ws, 0, 128, stream);

    router_main<<<NBLOCKS, NTHREADS, 0, stream>>>(x, wg, out_idx, out_w, imp_g, cnt_g);
    mask_loss_kernel<<<(NASSIGN + NTHREADS - 1) / NTHREADS, NTHREADS, 0, stream>>>(
        out_idx, out_w, mask, loss, imp_g, cnt_g);
}